// Round 6
// baseline (138.711 us; speedup 1.0000x reference)
//
#include <hip/hip_runtime.h>

typedef float f32x4 __attribute__((ext_vector_type(4)));
typedef short bf16x8 __attribute__((ext_vector_type(8)));   // 8 bf16 in 4 VGPRs (MFMA A/B operand)
typedef unsigned short u16x4 __attribute__((ext_vector_type(4)));

#define NS 8192
#define NB 16
#define NE 128
// log2(e)/sqrt(8192), folded into Wk/bk by the prelude
#define SCALE_K (1.4426950408889634f / 90.50966799187809f)

// Pack two f32 -> two bf16 RNE-ish (round-half-up via +0x8000; perm takes high halves).
__device__ __forceinline__ unsigned pack_bf16_rn(float lo, float hi) {
  union { float f; unsigned u; } a, b; a.f = lo; b.f = hi;
  return __builtin_amdgcn_perm(b.u + 0x8000u, a.u + 0x8000u, 0x07060302u);
}
// Truncating pack (bias cancels in p/l since l is summed from these same bf16 values)
__device__ __forceinline__ unsigned pack_bf16_tr(float lo, float hi) {
  union { float f; unsigned u; } a, b; a.f = lo; b.f = hi;
  return __builtin_amdgcn_perm(b.u, a.u, 0x07060302u);
}
__device__ __forceinline__ bf16x8 frag_from_f32(const float* p) {
  f32x4 lo = *(const f32x4*)p;
  f32x4 hi = *(const f32x4*)(p + 4);
  union { bf16x8 v; unsigned u[4]; } r;
  r.u[0] = pack_bf16_rn(lo[0], lo[1]);
  r.u[1] = pack_bf16_rn(lo[2], lo[3]);
  r.u[2] = pack_bf16_rn(hi[0], hi[1]);
  r.u[3] = pack_bf16_rn(hi[2], hi[3]);
  return r.v;
}
__device__ __forceinline__ u16x4 pack4_rn(f32x4 v) {
  union { u16x4 s; unsigned u[2]; } r;
  r.u[0] = pack_bf16_rn(v[0], v[1]);
  r.u[1] = pack_bf16_rn(v[2], v[3]);
  return r.s;
}
__device__ __forceinline__ u16x4 pack4_tr(f32x4 v) {
  union { u16x4 s; unsigned u[2]; } r;
  r.u[0] = pack_bf16_tr(v[0], v[1]);
  r.u[1] = pack_bf16_tr(v[2], v[3]);
  return r.s;
}

// ---------- prelude: W -> bf16 fragments in d_ws (once per launch) ----------
// wsW layout: [mat(2)][ntile(8)][ks(4)][lane(64)][8 shorts]  -> frag load = 1 coalesced b128
// Wk, bk pre-scaled by SCALE_K so softmax is exp2(score) with no per-element multiply.
__global__ __launch_bounds__(256)
void nsa_prep(const float* __restrict__ Wk, const float* __restrict__ bk,
              const float* __restrict__ Wv, const float* __restrict__ bv,
              unsigned short* __restrict__ wsW, float* __restrict__ wsB)
{
  const int t    = blockIdx.x * 256 + threadIdx.x;   // 0..4095
  const int lane = t & 63, ks = (t >> 6) & 3, nt = (t >> 8) & 7, mat = (t >> 11) & 1;
  const int q = lane >> 4, ln = lane & 15;
  const float sc = mat ? 1.0f : SCALE_K;
  const float* W = (mat ? Wv : Wk) + (nt * 16 + ln) * NE + ks * 32 + q * 8;
  union { bf16x8 v; unsigned u[4]; } r;
  #pragma unroll
  for (int i = 0; i < 4; ++i)
    r.u[i] = pack_bf16_rn(W[2 * i] * sc, W[2 * i + 1] * sc);
  *(bf16x8*)(wsW + t * 8) = r.v;
  if (t < NE)          wsB[t] = bk[t] * SCALE_K;
  else if (t < 2 * NE) wsB[t] = bv[t - NE];
}

// ---------- main fused kernel ----------
// GS=1: 4 waves/block, one s per block, 20.5 KiB LDS -> 7 blocks/CU (28 waves).
// Stage: wave w loads x rows b = 4w..4w+3 once -> bf16 -> XOR-swizzled xs.
// KV: wave w computes n-tiles {2w, 2w+1} (A-frags from xs).
// Attention: wave w handles eb = {2w, 2w+1} of this s.
// P buffers: wave0 -> dead V slice, wave1 -> dead xs, waves 2,3 -> pbuf.
__global__ __launch_bounds__(256, 4)
void nsa_fused(const float* __restrict__ x,
               const unsigned short* __restrict__ wsW,
               const float* __restrict__ wsB,
               float* __restrict__ out)
{
  // kt: [mat(2)][e(128)][16 shorts] bf16, 16B-granule XOR swizzle per row.
  __shared__ __align__(16) unsigned short kt[2 * NE * 16];   // 8 KiB (K slice, V slice)
  __shared__ __align__(16) unsigned short xs[NB * NE];       // 4 KiB x-stage (bf16)
  __shared__ __align__(16) unsigned short pbuf[2 * NB * NE]; // 8 KiB: P for waves 2,3

  const int tid  = threadIdx.x;
  const int wave = tid >> 6;          // 0..3
  const int lane = tid & 63;
  const int q    = lane >> 4;
  const int ln   = lane & 15;
  const int g    = (ln >> 2) & 1;     // kt swizzle group bit
  const int s0   = blockIdx.x;        // one s per block

  // ---------------- x staging: global -> bf16 -> xs ----------------
  // xs layout: [b(16)][granule gr=(L^b)&15][8 shorts], L = ks*4+sq (f-granule).
  // 16-lane groups read one contiguous 512B x-row; LDS writes conflict-free.
  {
    const int t  = lane & 15;          // L = ks*4+sq
    const int ks = t >> 2, sq = t & 3;
    const int b  = wave * 4 + q;       // 4 rows per wave
    const float* xp = x + (s0 * NB + b) * NE + ks * 32 + sq * 8;
    bf16x8 v = frag_from_f32(xp);
    const int gr = (t ^ b) & 15;
    *(bf16x8*)&xs[b * 128 + gr * 8] = v;
  }
  __syncthreads();

  bf16x8 xf[4];   // own-s A-frags (KV A operand, PV A operand)
  #pragma unroll
  for (int ks = 0; ks < 4; ++ks) {
    const int gr = ((ks * 4 + q) ^ ln) & 15;
    xf[ks] = *(const bf16x8*)&xs[ln * 128 + gr * 8];
  }

  // ---------------- KV phase: wave w -> n-tiles 2w, 2w+1 ----------------
  {
    const int o = (((q >> 1) ^ g) << 3) + ((q & 1) << 2);   // kt swizzled 8B-write offset
    #pragma unroll
    for (int ntl = 0; ntl < 2; ++ntl) {
      const int nt = wave * 2 + ntl;
      #pragma unroll
      for (int mat = 0; mat < 2; ++mat) {
        bf16x8 wf[4];
        #pragma unroll
        for (int ks = 0; ks < 4; ++ks)
          wf[ks] = *(const bf16x8*)(wsW + (((mat * 8 + nt) * 4 + ks) * 64 + lane) * 8);
        const float bias = wsB[mat * NE + nt * 16 + ln];
        f32x4 acc = { bias, bias, bias, bias };
        #pragma unroll
        for (int ks = 0; ks < 4; ++ks)
          acc = __builtin_amdgcn_mfma_f32_16x16x32_bf16(xf[ks], wf[ks], acc, 0, 0, 0);
        const int e = nt * 16 + ln;
        *(u16x4*)&kt[(mat * NE + e) * 16 + o] = pack4_rn(acc);
      }
    }
  }
  __syncthreads();

  const int ro = ((q ^ g) & 1) << 3;   // kt swizzled 16B-read offset within row

  // vf: A-frags for scores^T = V^T K'; k = b (16 real + 16 zero via zero REGISTER).
  // All waves must finish before V slice / xs are overwritten with P -> barrier.
  bf16x8 vf[8];
  {
    const bf16x8 zfrag = { 0, 0, 0, 0, 0, 0, 0, 0 };
    #pragma unroll
    for (int mt = 0; mt < 8; ++mt)
      vf[mt] = (q < 2) ? *(const bf16x8*)&kt[(NE + mt * 16 + ln) * 16 + ro] : zfrag;
  }
  __syncthreads();

  // ---------------- attention phase: wave handles eb = 2w, 2w+1 ----------------
  {
    unsigned short* pw = (wave == 0) ? &kt[NE * 16]
                       : (wave == 1) ? xs
                       : &pbuf[(wave - 2) * (NB * NE)];

    // all-ones A-frag: D[m][e] = sum_f P[e][f] -> softmax denominator on the MFMA pipe
    union { bf16x8 v; unsigned u[4]; } onesu;
    #pragma unroll
    for (int i = 0; i < 4; ++i) onesu.u[i] = 0x3F803F80u;   // bf16 1.0 pairs
    const bf16x8 ones = onesu.v;

    // kf: A's k>=16 half is zero, so B's k>=16 values are don't-care -> no lane select
    const unsigned short* kbase = &kt[ln * 16 + ro];

    bf16x8 kf = *(const bf16x8*)(kbase + (wave * 2) * 256);

    #pragma unroll
    for (int ebi = 0; ebi < 2; ++ebi) {
      const int eb = wave * 2 + ebi;
      const bf16x8 kcur = kf;
      if (ebi < 1) kf = *(const bf16x8*)(kbase + (eb + 1) * 256);   // prefetch next

      // streaming scores -> exp2 -> truncated bf16 P -> LDS (no max-sub; scale pre-folded)
      #pragma unroll
      for (int mt = 0; mt < 8; ++mt) {
        const f32x4 z = { 0.f, 0.f, 0.f, 0.f };
        f32x4 sc = __builtin_amdgcn_mfma_f32_16x16x32_bf16(vf[mt], kcur, z, 0, 0, 0);
        f32x4 p;
        #pragma unroll
        for (int r = 0; r < 4; ++r) p[r] = __builtin_amdgcn_exp2f(sc[r]);
        const int col = (mt * 16 + q * 4 + 8 * ln) & 127;
        *(u16x4*)&pw[ln * 128 + col] = pack4_tr(p);
      }

      // out n-tile: D[m=b][n=e] = sum_f X[b][f] * P[e][f]; denominator via ones-MFMA
      f32x4 oacc = { 0.f, 0.f, 0.f, 0.f };
      f32x4 lacc = { 0.f, 0.f, 0.f, 0.f };
      #pragma unroll
      for (int ks = 0; ks < 4; ++ks) {
        const int col = (ks * 32 + q * 8 + 8 * ln) & 127;
        const bf16x8 pf = *(const bf16x8*)&pw[ln * 128 + col];
        oacc = __builtin_amdgcn_mfma_f32_16x16x32_bf16(xf[ks], pf, oacc, 0, 0, 0);
        lacc = __builtin_amdgcn_mfma_f32_16x16x32_bf16(ones,   pf, lacc, 0, 0, 0);
      }
      const float inv_l = __builtin_amdgcn_rcpf(lacc[0]);   // D col = ln -> lane-matched
      const int e = eb * 16 + ln;
      #pragma unroll
      for (int r = 0; r < 4; ++r)
        out[(s0 * NB + q * 4 + r) * NE + e] = oacc[r] * inv_l;
    }
  }
}

extern "C" void kernel_launch(void* const* d_in, const int* in_sizes, int n_in,
                              void* d_out, int out_size, void* d_ws, size_t ws_size,
                              hipStream_t stream)
{
  const float* x  = (const float*)d_in[0];
  const float* Wk = (const float*)d_in[1];
  const float* bk = (const float*)d_in[2];
  const float* Wv = (const float*)d_in[3];
  const float* bv = (const float*)d_in[4];
  float* o = (float*)d_out;

  unsigned short* wsW = (unsigned short*)d_ws;                  // 64 KiB
  float*          wsB = (float*)((char*)d_ws + 64 * 1024);      // 1 KiB

  hipLaunchKernelGGL(nsa_prep, dim3(16), dim3(256), 0, stream, Wk, bk, Wv, bv, wsW, wsB);
  hipLaunchKernelGGL(nsa_fused, dim3(NS), dim3(256), 0, stream, x, wsW, wsB, o);
}

// Round 7
// 131.562 us; speedup vs baseline: 1.0543x; 1.0543x over previous
//
#include <hip/hip_runtime.h>

typedef float f32x4 __attribute__((ext_vector_type(4)));
typedef short bf16x8 __attribute__((ext_vector_type(8)));   // 8 bf16 in 4 VGPRs (MFMA A/B operand)
typedef unsigned short u16x4 __attribute__((ext_vector_type(4)));

#define NS 8192
#define NB 16
#define NE 128
#define GS 4   // s-values per block (two waves per s)
// log2(e)/sqrt(8192), folded into Wk/bk by the prelude
#define SCALE_K (1.4426950408889634f / 90.50966799187809f)

// Pack two f32 -> two bf16 RNE-ish (round-half-up via +0x8000; perm takes high halves).
__device__ __forceinline__ unsigned pack_bf16_rn(float lo, float hi) {
  union { float f; unsigned u; } a, b; a.f = lo; b.f = hi;
  return __builtin_amdgcn_perm(b.u + 0x8000u, a.u + 0x8000u, 0x07060302u);
}
// Truncating pack (bias cancels in p/l since l is summed from these same bf16 values)
__device__ __forceinline__ unsigned pack_bf16_tr(float lo, float hi) {
  union { float f; unsigned u; } a, b; a.f = lo; b.f = hi;
  return __builtin_amdgcn_perm(b.u, a.u, 0x07060302u);
}
__device__ __forceinline__ bf16x8 frag_from_f32(const float* p) {
  f32x4 lo = *(const f32x4*)p;
  f32x4 hi = *(const f32x4*)(p + 4);
  union { bf16x8 v; unsigned u[4]; } r;
  r.u[0] = pack_bf16_rn(lo[0], lo[1]);
  r.u[1] = pack_bf16_rn(lo[2], lo[3]);
  r.u[2] = pack_bf16_rn(hi[0], hi[1]);
  r.u[3] = pack_bf16_rn(hi[2], hi[3]);
  return r.v;
}
__device__ __forceinline__ u16x4 pack4_rn(f32x4 v) {
  union { u16x4 s; unsigned u[2]; } r;
  r.u[0] = pack_bf16_rn(v[0], v[1]);
  r.u[1] = pack_bf16_rn(v[2], v[3]);
  return r.s;
}
__device__ __forceinline__ u16x4 pack4_tr(f32x4 v) {
  union { u16x4 s; unsigned u[2]; } r;
  r.u[0] = pack_bf16_tr(v[0], v[1]);
  r.u[1] = pack_bf16_tr(v[2], v[3]);
  return r.s;
}

// ---------- prelude: W -> bf16 fragments in d_ws (once per launch) ----------
// wsW layout: [mat(2)][ntile(8)][ks(4)][lane(64)][8 shorts]  -> frag load = 1 coalesced b128
// Wk, bk pre-scaled by SCALE_K so softmax is exp2(score) with no per-element multiply.
__global__ __launch_bounds__(256)
void nsa_prep(const float* __restrict__ Wk, const float* __restrict__ bk,
              const float* __restrict__ Wv, const float* __restrict__ bv,
              unsigned short* __restrict__ wsW, float* __restrict__ wsB)
{
  const int t    = blockIdx.x * 256 + threadIdx.x;   // 0..4095
  const int lane = t & 63, ks = (t >> 6) & 3, nt = (t >> 8) & 7, mat = (t >> 11) & 1;
  const int q = lane >> 4, ln = lane & 15;
  const float sc = mat ? 1.0f : SCALE_K;
  const float* W = (mat ? Wv : Wk) + (nt * 16 + ln) * NE + ks * 32 + q * 8;
  union { bf16x8 v; unsigned u[4]; } r;
  #pragma unroll
  for (int i = 0; i < 4; ++i)
    r.u[i] = pack_bf16_rn(W[2 * i] * sc, W[2 * i + 1] * sc);
  *(bf16x8*)(wsW + t * 8) = r.v;
  if (t < NE)          wsB[t] = bk[t] * SCALE_K;
  else if (t < 2 * NE) wsB[t] = bv[t - NE];
}

// ---------- main fused kernel ----------
// 8 waves/block (R5 structure, best measured 43.5us). Changes this round:
// (1) P-buffer swizzle c(f,ln) = (f&7) | (((f>>3 ^ ln)&15)<<3): uniform bank
//     distribution on both the b64 write and b128 read (was 4-way-ish).
// (2) s_setprio(1) around the PV MFMA cluster (waves drift in eb loop).
__global__ __launch_bounds__(512, 4)
void nsa_fused(const float* __restrict__ x,
               const unsigned short* __restrict__ wsW,
               const float* __restrict__ wsB,
               float* __restrict__ out)
{
  // Kt/Vt: [mat(2)][s(GS)][e(128)][16 shorts] bf16, 16B-granule XOR swizzle per row.
  __shared__ __align__(16) unsigned short kt[2 * GS * NE * 16];   // 32 KiB
  __shared__ __align__(16) unsigned short xs[GS * NB * NE];       // 16 KiB x-stage (bf16)
  __shared__ __align__(16) unsigned short zbuf[32];               // 64B zeros: K-dim pad

  const int tid  = threadIdx.x;
  const int wave = tid >> 6;          // 0..7
  const int lane = tid & 63;
  const int q    = lane >> 4;
  const int ln   = lane & 15;
  const int g    = (ln >> 2) & 1;     // kt swizzle group bit
  const int s0   = blockIdx.x * GS;
  const int smt  = wave & 3;          // s this wave stages/attends
  const int h    = wave >> 2;         // 0: rows b 0-7 & eb 0-3;  1: rows b 8-15 & eb 4-7

  if (tid < 32) zbuf[tid] = 0;

  // ---------------- x staging: global -> bf16 -> xs (once per block) ----------------
  // xs layout: [s(4)][b(16)][granule gr=((ks*4+q)^b)&15][8 shorts]
  {
    const int c  = lane >> 5;          // 0..1 -> e-half
    const int sq = (lane >> 3) & 3;    // target-frag q
    const int bl = lane & 7;
    const int b  = h * 8 + bl;
    const float* xp = x + ((s0 + smt) * NB + b) * NE + c * 64 + sq * 8;
    #pragma unroll
    for (int ksp = 0; ksp < 2; ++ksp) {
      const int ks = c * 2 + ksp;
      bf16x8 v = frag_from_f32(xp + ksp * 32);
      const int gr = ((ks * 4 + sq) ^ b) & 15;
      *(bf16x8*)&xs[smt * 2048 + b * 128 + gr * 8] = v;
    }
  }
  __syncthreads();

  bf16x8 xf[4];   // ends as own-s A-frags (mt order ends at smt)

  // ---------------- KV phase ----------------
  {
    bf16x8 wf[2][4];   // nt = wave: 8 weight frags, single b128 loads
    float  bias[2];
    #pragma unroll
    for (int mat = 0; mat < 2; ++mat) {
      #pragma unroll
      for (int ks = 0; ks < 4; ++ks)
        wf[mat][ks] = *(const bf16x8*)(wsW + (((mat * 8 + wave) * 4 + ks) * 64 + lane) * 8);
      bias[mat] = wsB[mat * NE + wave * 16 + ln];
    }

    const int o = (((q >> 1) ^ g) << 3) + ((q & 1) << 2);   // kt swizzled 8B-write offset
    const int e = wave * 16 + ln;
    #pragma unroll
    for (int i = 0; i < GS; ++i) {
      const int mt = (smt + 1 + i) & (GS - 1);     // end at mt==smt so xf == own-s frags
      #pragma unroll
      for (int ks = 0; ks < 4; ++ks) {
        const int gr = ((ks * 4 + q) ^ ln) & 15;
        xf[ks] = *(const bf16x8*)&xs[mt * 2048 + ln * 128 + gr * 8];
      }
      #pragma unroll
      for (int mat = 0; mat < 2; ++mat) {
        f32x4 acc = { bias[mat], bias[mat], bias[mat], bias[mat] };
        #pragma unroll
        for (int ks = 0; ks < 4; ++ks)
          acc = __builtin_amdgcn_mfma_f32_16x16x32_bf16(xf[ks], wf[mat][ks], acc, 0, 0, 0);
        *(u16x4*)&kt[((mat * GS + mt) * NE + e) * 16 + o] = pack4_rn(acc);
      }
    }
  }
  __syncthreads();

  const int ro = ((q ^ g) & 1) << 3;   // kt swizzled 16B-read offset within row

  // vf: BOTH pair members read the V slice of smt; must complete before that slice
  // (h=0) / the xs slice (h=1) is overwritten with P -> second barrier below.
  bf16x8 vf[8];
  #pragma unroll
  for (int mt = 0; mt < 8; ++mt) {
    const unsigned short* src =
        (q < 2) ? &kt[((GS + smt) * NE + mt * 16 + ln) * 16 + ro] : zbuf;
    vf[mt] = *(const bf16x8*)src;
  }
  __syncthreads();

  // ---------------- attention phase: wave handles eb = h*4 .. h*4+3 of s0+smt ----------------
  {
    const int sw = s0 + smt;
    unsigned short* pw = h ? &xs[smt * 2048] : &kt[(GS + smt) * NE * 16];

    // all-ones A-frag: D[m][e] = sum_f P[e][f] -> softmax denominator on the MFMA pipe
    union { bf16x8 v; unsigned u[4]; } onesu;
    #pragma unroll
    for (int i = 0; i < 4; ++i) onesu.u[i] = 0x3F803F80u;   // bf16 1.0 pairs
    const bf16x8 ones = onesu.v;

    // kf: A's k>=16 half is zero, so B's k>=16 values are don't-care -> no lane select
    const unsigned short* kbase = &kt[(smt * NE + ln) * 16 + ro];

    bf16x8 kf = *(const bf16x8*)(kbase + h * 4 * 256);

    #pragma unroll 2
    for (int ebi = 0; ebi < 4; ++ebi) {
      const int eb = h * 4 + ebi;
      const bf16x8 kcur = kf;
      if (ebi < 3) kf = *(const bf16x8*)(kbase + (eb + 1) * 256);   // prefetch next

      // streaming scores -> exp2 -> truncated bf16 P -> LDS.
      // P storage col c(f,ln) = (f&7) | (((f>>3 ^ ln)&15)<<3): f-runs of 4 (write)
      // and 8 (read) contiguous; bank use uniform (min-phase) on both sides.
      #pragma unroll
      for (int mt = 0; mt < 8; ++mt) {
        const f32x4 z = { 0.f, 0.f, 0.f, 0.f };
        f32x4 sc = __builtin_amdgcn_mfma_f32_16x16x32_bf16(vf[mt], kcur, z, 0, 0, 0);
        f32x4 p;
        #pragma unroll
        for (int r = 0; r < 4; ++r) p[r] = __builtin_amdgcn_exp2f(sc[r]);
        const int cw = ((q & 1) << 2) | (((((mt << 1) | (q >> 1)) ^ ln) & 15) << 3);
        *(u16x4*)&pw[ln * 128 + cw] = pack4_tr(p);
      }

      // out n-tile: D[m=b][n=e] = sum_f X[b][f] * P[e][f]; denominator via ones-MFMA
      f32x4 oacc = { 0.f, 0.f, 0.f, 0.f };
      f32x4 lacc = { 0.f, 0.f, 0.f, 0.f };
      __builtin_amdgcn_s_setprio(1);
      #pragma unroll
      for (int ks = 0; ks < 4; ++ks) {
        const int cr = ((((ks << 2) | q) ^ ln) & 15) << 3;
        const bf16x8 pf = *(const bf16x8*)&pw[ln * 128 + cr];
        oacc = __builtin_amdgcn_mfma_f32_16x16x32_bf16(xf[ks], pf, oacc, 0, 0, 0);
        lacc = __builtin_amdgcn_mfma_f32_16x16x32_bf16(ones,   pf, lacc, 0, 0, 0);
      }
      __builtin_amdgcn_s_setprio(0);
      const float inv_l = __builtin_amdgcn_rcpf(lacc[0]);   // D col = ln -> lane-matched
      const int e = eb * 16 + ln;
      #pragma unroll
      for (int r = 0; r < 4; ++r)
        out[(sw * NB + q * 4 + r) * NE + e] = oacc[r] * inv_l;
    }
  }
}

extern "C" void kernel_launch(void* const* d_in, const int* in_sizes, int n_in,
                              void* d_out, int out_size, void* d_ws, size_t ws_size,
                              hipStream_t stream)
{
  const float* x  = (const float*)d_in[0];
  const float* Wk = (const float*)d_in[1];
  const float* bk = (const float*)d_in[2];
  const float* Wv = (const float*)d_in[3];
  const float* bv = (const float*)d_in[4];
  float* o = (float*)d_out;

  unsigned short* wsW = (unsigned short*)d_ws;                  // 64 KiB
  float*          wsB = (float*)((char*)d_ws + 64 * 1024);      // 1 KiB

  hipLaunchKernelGGL(nsa_prep, dim3(16), dim3(256), 0, stream, Wk, bk, Wv, bv, wsW, wsB);
  hipLaunchKernelGGL(nsa_fused, dim3(NS / GS), dim3(512), 0, stream, x, wsW, wsB, o);
}